// Round 6
// baseline (102.808 us; speedup 1.0000x reference)
//
#include <hip/hip_runtime.h>

// L1 attention: attn[b,s,t,h] = -sum_w |q[b,s,h,w] - k[b,t,h,w]| / sqrt(W)
// B=1, S=T=1024, H=8, W=32, fp32 in / fp32 out.
//
// Round 6: break the broadcast/occupancy trap -- NO LDS anywhere.
// - lane = t (64 t per block), wave = h-pair (wave w -> h = 2w, 2w+1).
// - q row address is WAVE-UNIFORM per si -> s_load into SGPRs (q costs no
//   VGPRs, no LDS pipe, no per-lane load latency). readfirstlane pins it.
// - k: 2 rows per lane (64 VGPR), loaded once, severed from memory so the
//   allocator cannot sink the loads into the si loop.
// - stores: float2 per lane, 32B lane stride (1/4 sector efficiency, ~4 us
//   L2-side, overlapped). Plain stores so L2 write-combines; NT would not.
// - ~85 VGPR, 0 LDS -> 5-6 waves/SIMD latency hiding (vs 2 in R3-R5).

constexpr int S_DIM = 1024;
constexpr int T_DIM = 1024;
constexpr int H_DIM = 8;
constexpr int W_DIM = 32;
constexpr int TBLK = 64;   // t per block (= lanes per wave)
constexpr int SBLK = 16;   // s per block

__global__ __launch_bounds__(256, 3)
void l1attn_kernel(const float* __restrict__ q,
                   const float* __restrict__ k,
                   float* __restrict__ out) {
    const int tid  = threadIdx.x;
    const int lane = tid & 63;
    const int wv   = tid >> 6;                                   // 0..3
    const int h0   = __builtin_amdgcn_readfirstlane(wv * 2);     // uniform h-pair base
    const int t    = blockIdx.x * TBLK + lane;
    const int s0   = blockIdx.y * SBLK;

    // ---- two k rows (t, h0) and (t, h0+1) -> 64 VGPRs ----
    float kr[2][W_DIM];
    #pragma unroll
    for (int u = 0; u < 2; ++u) {
        const float4* krow =
            (const float4*)(k + ((size_t)t * H_DIM + h0 + u) * W_DIM);
        #pragma unroll
        for (int j = 0; j < 8; ++j) {
            float4 v = krow[j];
            kr[u][4 * j + 0] = v.x;
            kr[u][4 * j + 1] = v.y;
            kr[u][4 * j + 2] = v.z;
            kr[u][4 * j + 3] = v.w;
        }
    }
    #pragma unroll
    for (int u = 0; u < 2; ++u)
        #pragma unroll
        for (int w = 0; w < W_DIM; ++w)
            asm volatile("" : "+v"(kr[u][w]));

    const float nscale = -0.17677669529663688f;  // -1/sqrt(32)

    #pragma unroll 1
    for (int si = 0; si < SBLK; ++si) {
        const int s = s0 + si;
        // Wave-uniform q pointer: rows (s, h0) and (s, h0+1), contiguous 256B.
        const float* qrow = q + ((size_t)s * H_DIM + h0) * W_DIM;

        float qv[2][W_DIM];
        #pragma unroll
        for (int u = 0; u < 2; ++u)
            #pragma unroll
            for (int w = 0; w < W_DIM; ++w)
                qv[u][w] = qrow[u * W_DIM + w];   // uniform -> s_load_dwordxN

        float a00 = 0.f, a01 = 0.f, a10 = 0.f, a11 = 0.f;  // 4 chains
        #pragma unroll
        for (int w = 0; w < W_DIM; w += 2) {
            a00 += fabsf(qv[0][w]     - kr[0][w]);
            a01 += fabsf(qv[0][w + 1] - kr[0][w + 1]);
            a10 += fabsf(qv[1][w]     - kr[1][w]);
            a11 += fabsf(qv[1][w + 1] - kr[1][w + 1]);
        }

        float2 r;
        r.x = (a00 + a01) * nscale;
        r.y = (a10 + a11) * nscale;
        *(float2*)(&out[((size_t)s * T_DIM + t) * H_DIM + h0]) = r;
    }
}

extern "C" void kernel_launch(void* const* d_in, const int* in_sizes, int n_in,
                              void* d_out, int out_size, void* d_ws, size_t ws_size,
                              hipStream_t stream) {
    const float* q = (const float*)d_in[0];
    const float* k = (const float*)d_in[1];
    float* out = (float*)d_out;
    dim3 grid(T_DIM / TBLK, S_DIM / SBLK);  // (16, 64) = 1024 blocks
    l1attn_kernel<<<grid, dim3(256, 1, 1), 0, stream>>>(q, k, out);
}

// Round 7
// 82.056 us; speedup vs baseline: 1.2529x; 1.2529x over previous
//
#include <hip/hip_runtime.h>

// L1 attention: attn[b,s,t,h] = -sum_w |q[b,s,h,w] - k[b,t,h,w]| / sqrt(W)
// B=1, S=T=1024, H=8, W=32, fp32 in / fp32 out.
//
// Round 7 = R4 + register double-buffered q (the one thing R3-R5 lacked:
// in-loop latency hiding). Per si: issue next-si ds_reads, compute current
// from registers already loaded one full compute-phase (580 cy) earlier --
// compiler emits counted lgkmcnt so the wait is free. Named qA/qB buffers,
// all indices compile-time (no dynamic-index scratch).
// - CT=4 k rows/thread (128 VGPR, severed), 16 KB swizzled q LDS tile,
//   conflict-free staging + broadcast reads (verified bank math, R1/R2: 0).
// - NT stores, 64-contiguous-dword per wave.
// - ~220 VGPR -> __launch_bounds__(256,2); 512 blocks = 2/CU, 8 waves/CU.
// Model: per CU per si: VALU 1160 cy/SIMD > LDS 768 cy -> VALU-bound,
// ~9 us kernel.

constexpr int S_DIM = 1024;
constexpr int T_DIM = 1024;
constexpr int H_DIM = 8;
constexpr int W_DIM = 32;
constexpr int TB = 128;  // t per block (4 per thread)
constexpr int SB = 16;   // s per block
constexpr int CT = 4;    // k rows per thread

__global__ __launch_bounds__(256, 2)
void l1attn_kernel(const float* __restrict__ q,
                   const float* __restrict__ k,
                   float* __restrict__ out) {
    const int tid  = threadIdx.x;
    const int h    = tid & 7;
    const int tsub = tid >> 3;                 // 0..31
    const int t0   = blockIdx.x * TB;
    const int s0   = blockIdx.y * SB;

    __shared__ float4 qlds[SB * H_DIM * (W_DIM / 4)];  // 1024 float4 = 16 KB

    // ---- four k rows -> 128 VGPRs, severed so they stay resident ----
    float kreg[CT][W_DIM];
    #pragma unroll
    for (int u = 0; u < CT; ++u) {
        const float4* krow =
            (const float4*)(k + ((t0 + u * 32 + tsub) * H_DIM + h) * W_DIM);
        #pragma unroll
        for (int j = 0; j < 8; ++j) {
            float4 v = krow[j];
            kreg[u][4 * j + 0] = v.x;
            kreg[u][4 * j + 1] = v.y;
            kreg[u][4 * j + 2] = v.z;
            kreg[u][4 * j + 3] = v.w;
        }
    }
    #pragma unroll
    for (int u = 0; u < CT; ++u)
        #pragma unroll
        for (int w = 0; w < W_DIM; ++w)
            asm volatile("" : "+v"(kreg[u][w]));

    // ---- stage q tile (16 KB, contiguous) into swizzled LDS ----
    const float4* q4 = (const float4*)(q + (size_t)s0 * H_DIM * W_DIM);
    #pragma unroll
    for (int p = 0; p < 4; ++p) {
        int f = p * 256 + tid;   // float4 index, 0..1023
        int r = f >> 3;          // row = si*8 + h_row
        int j = f & 7;           // 16B chunk in row
        qlds[r * 8 + (j ^ (r & 7))] = q4[f];
    }
    __syncthreads();

    const float nscale = -0.17677669529663688f;  // -1/sqrt(32)

    auto loadq = [&](int si, float4* dst) {
        const float4* qrow = qlds + (si * H_DIM + h) * 8;
        #pragma unroll
        for (int j = 0; j < 8; ++j) dst[j] = qrow[j ^ h];
    };

    auto compute_store = [&](int si, const float4* qv) {
        float a[CT][4];
        #pragma unroll
        for (int u = 0; u < CT; ++u)
            a[u][0] = a[u][1] = a[u][2] = a[u][3] = 0.f;
        #pragma unroll
        for (int j = 0; j < 8; ++j) {
            #pragma unroll
            for (int u = 0; u < CT; ++u) {
                a[u][0] += fabsf(qv[j].x - kreg[u][4 * j + 0]);
                a[u][1] += fabsf(qv[j].y - kreg[u][4 * j + 1]);
                a[u][2] += fabsf(qv[j].z - kreg[u][4 * j + 2]);
                a[u][3] += fabsf(qv[j].w - kreg[u][4 * j + 3]);
            }
        }
        const int s = s0 + si;
        #pragma unroll
        for (int u = 0; u < CT; ++u) {
            const float r =
                ((a[u][0] + a[u][1]) + (a[u][2] + a[u][3])) * nscale;
            __builtin_nontemporal_store(
                r, &out[(s * T_DIM + t0 + u * 32 + tsub) * H_DIM + h]);
        }
    };

    float4 qA[8], qB[8];
    loadq(0, qA);
    #pragma unroll 1
    for (int si = 0; si < SB; si += 2) {
        loadq(si + 1, qB);              // prefetch odd
        compute_store(si, qA);          // compute even (loaded last phase)
        loadq((si + 2) & (SB - 1), qA); // prefetch next even (wraps, harmless)
        compute_store(si + 1, qB);      // compute odd
    }
}

extern "C" void kernel_launch(void* const* d_in, const int* in_sizes, int n_in,
                              void* d_out, int out_size, void* d_ws, size_t ws_size,
                              hipStream_t stream) {
    const float* q = (const float*)d_in[0];
    const float* k = (const float*)d_in[1];
    float* out = (float*)d_out;
    dim3 grid(T_DIM / TB, S_DIM / SB);  // (8, 64) = 512 blocks
    l1attn_kernel<<<grid, dim3(256, 1, 1), 0, stream>>>(q, k, out);
}